// Round 9
// baseline (165.319 us; speedup 1.0000x reference)
//
#include <hip/hip_runtime.h>
#include <math.h>

// CapsuleLayer dynamic routing, fused. R9: MB=2 at T=1024, tiny LDS.
// Ledger: allocator pins VGPR<=64 in every config (R2/R3/R6/R7) -> demand
// must fit 64. R8 (clean, 61% occ) sits ~1.5x above its own L2 floor:
// W traffic 2560 blocks x 589 KB = 1.51 GB (~44 us at 34.5 TB/s). R5's
// "traffic halving doesn't help" was confounded (75 KB LDS -> 1 block/CU).
// This config halves W traffic with NO occupancy cost: pri = 2 batches x
// 4.5 tiles x 4 = 40 regs (+transients ~58 <= 64, no spill); LDS 11.5 KB;
// 1024 thr x 2 blocks/CU = 32 waves = 100% occupancy. Each W float4 now
// feeds 8 FMAs. W floor: 1280 x 589 KB = 755 MB -> ~22 us.
// c-major blocks: 128 consecutive blocks share W[c] in L2.

#define NC 10
#define NR 1152
#define IC 8
#define OC 16
#define NITER 3
#define T 1024
#define MB 2

__device__ __forceinline__ float wave_sum(float v) {
#pragma unroll
    for (int m = 1; m <= 32; m <<= 1) v += __shfl_xor(v, m, 64);
    return v;
}
__device__ __forceinline__ float wave_max(float v) {
#pragma unroll
    for (int m = 1; m <= 32; m <<= 1) v = fmaxf(v, __shfl_xor(v, m, 64));
    return v;
}

__global__ __launch_bounds__(T) void caps_route(
    const float* __restrict__ x,   // [B, NR, IC]
    const float* __restrict__ W,   // [NC, NR, IC, OC]
    float* __restrict__ out)       // [B, NC, OC]
{
    __shared__ float logit0[NR], logit1[NR]; // collapsed logits, both batches
    __shared__ float red[2 * 256];           // [2][16 waves][16 o]
    __shared__ float vout[2 * OC];

    const int t    = threadIdx.x;
    const int og   = t & 3;        // o-quad (o = og*4+j)
    const int rr   = t >> 2;       // 0..255
    const int lane = t & 63;
    const int wid  = t >> 6;       // 0..15
    const bool has4 = (rr < 128);  // tail tile r=1024+rr; wave-uniform (waves 0..7)

    const int c  = blockIdx.x >> 7;          // c-major
    const int b0 = (blockIdx.x & 127) * 2;   // b1 = b0+1

    // ---------------- Phase A: priors from global x and W -------------------
    // r = rr + 256p (p<4), 1024+rr (tail, rr<128)
    const float4* __restrict__ xb0 = (const float4*)(x + (size_t)b0 * (NR * IC));
    const float4* __restrict__ xb1 = xb0 + NR * 2;   // next batch row
    const float4* __restrict__ wb  = (const float4*)(W + (size_t)c * (NR * IC * OC));
    const int r4 = has4 ? (1024 + rr) : 1151;        // clamped in-range; unused lanes

    float4 pri0[5], pri1[5];
#pragma unroll
    for (int p = 0; p < 5; ++p) {
        const int r = (p < 4) ? (rr + (p << 8)) : r4;
        float4 xa0 = xb0[2 * r], xc0 = xb0[2 * r + 1];
        float4 xa1 = xb1[2 * r], xc1 = xb1[2 * r + 1];
        float xv0[8] = {xa0.x, xa0.y, xa0.z, xa0.w, xc0.x, xc0.y, xc0.z, xc0.w};
        float xv1[8] = {xa1.x, xa1.y, xa1.z, xa1.w, xc1.x, xc1.y, xc1.z, xc1.w};
        const float4* wp = wb + (size_t)r * 32 + og; // float4 idx (r*8+i)*4+og
        float4 a0 = make_float4(0.f, 0.f, 0.f, 0.f);
        float4 a1 = make_float4(0.f, 0.f, 0.f, 0.f);
#pragma unroll
        for (int i = 0; i < 8; ++i) {
            float4 w = wp[i * 4];            // one load feeds both batches
            a0.x = fmaf(xv0[i], w.x, a0.x); a1.x = fmaf(xv1[i], w.x, a1.x);
            a0.y = fmaf(xv0[i], w.y, a0.y); a1.y = fmaf(xv1[i], w.y, a1.y);
            a0.z = fmaf(xv0[i], w.z, a0.z); a1.z = fmaf(xv1[i], w.z, a1.z);
            a0.w = fmaf(xv0[i], w.w, a0.w); a1.w = fmaf(xv1[i], w.w, a1.w);
        }
        pri0[p] = a0; pri1[p] = a1;          // p=4 garbage for !has4 — never read
    }

    // ---------------- Phase B: 3 routing iterations -------------------------
    for (int it = 0; it < NITER; ++it) {
        const bool uni = (it == 0);          // softmax of zeros = uniform
        float m0 = 0.f, m1 = 0.f, invd0 = 0.f, invd1 = 0.f;
        if (!uni) {
            float l0 = logit0[t], l1 = logit1[t];    // t covers 0..1023
            float lm0 = l0, lm1 = l1;
            if (t < 128) {                           // tail 1024..1151
                lm0 = fmaxf(lm0, logit0[1024 + t]);
                lm1 = fmaxf(lm1, logit1[1024 + t]);
            }
            lm0 = wave_max(lm0); lm1 = wave_max(lm1);
            if (lane == 0) { red[wid] = lm0; red[16 + wid] = lm1; }
            __syncthreads();
            m0 = red[0]; m1 = red[16];
#pragma unroll
            for (int w = 1; w < 16; ++w) {
                m0 = fmaxf(m0, red[w]); m1 = fmaxf(m1, red[16 + w]);
            }
            float e0 = __expf(l0 - m0), e1 = __expf(l1 - m1);
            if (t < 128) {
                e0 += __expf(logit0[1024 + t] - m0);
                e1 += __expf(logit1[1024 + t] - m1);
            }
            e0 = wave_sum(e0); e1 = wave_sum(e1);
            __syncthreads();                 // m reads done before red rewrite
            if (lane == 0) { red[wid] = e0; red[16 + wid] = e1; }
            __syncthreads();
            float d0 = red[0], d1 = red[16];
#pragma unroll
            for (int w = 1; w < 16; ++w) { d0 += red[w]; d1 += red[16 + w]; }
            invd0 = 1.f / d0; invd1 = 1.f / d1;
        }

        // s[o] partials, both batches
        float4 s0 = make_float4(0.f, 0.f, 0.f, 0.f);
        float4 s1 = make_float4(0.f, 0.f, 0.f, 0.f);
#pragma unroll
        for (int p = 0; p < 4; ++p) {
            float w0 = 1.0f, w1 = 1.0f;
            if (!uni) {
                const int r = rr + (p << 8);
                w0 = __expf(logit0[r] - m0);
                w1 = __expf(logit1[r] - m1);
            }
            s0.x = fmaf(w0, pri0[p].x, s0.x); s1.x = fmaf(w1, pri1[p].x, s1.x);
            s0.y = fmaf(w0, pri0[p].y, s0.y); s1.y = fmaf(w1, pri1[p].y, s1.y);
            s0.z = fmaf(w0, pri0[p].z, s0.z); s1.z = fmaf(w1, pri1[p].z, s1.z);
            s0.w = fmaf(w0, pri0[p].w, s0.w); s1.w = fmaf(w1, pri1[p].w, s1.w);
        }
        if (has4) {                          // wave-uniform tail tile
            float w0 = 1.0f, w1 = 1.0f;
            if (!uni) {
                w0 = __expf(logit0[1024 + rr] - m0);
                w1 = __expf(logit1[1024 + rr] - m1);
            }
            s0.x = fmaf(w0, pri0[4].x, s0.x); s1.x = fmaf(w1, pri1[4].x, s1.x);
            s0.y = fmaf(w0, pri0[4].y, s0.y); s1.y = fmaf(w1, pri1[4].y, s1.y);
            s0.z = fmaf(w0, pri0[4].z, s0.z); s1.z = fmaf(w1, pri1[4].z, s1.z);
            s0.w = fmaf(w0, pri0[4].w, s0.w); s1.w = fmaf(w1, pri1[4].w, s1.w);
        }
        // reduce over the 16 rr slots (same og) within each wave
#pragma unroll
        for (int msk = 4; msk <= 32; msk <<= 1) {
            s0.x += __shfl_xor(s0.x, msk, 64); s1.x += __shfl_xor(s1.x, msk, 64);
            s0.y += __shfl_xor(s0.y, msk, 64); s1.y += __shfl_xor(s1.y, msk, 64);
            s0.z += __shfl_xor(s0.z, msk, 64); s1.z += __shfl_xor(s1.z, msk, 64);
            s0.w += __shfl_xor(s0.w, msk, 64); s1.w += __shfl_xor(s1.w, msk, 64);
        }
        __syncthreads();                     // stats/prev-red reads done
        if (lane < 4) {                      // lane==og for these lanes
            ((float4*)red)[wid * 4 + og]         = s0; // red[wid*16+o]
            ((float4*)(red + 256))[wid * 4 + og] = s1;
        }
        __syncthreads();

        if (t < 2 * OC) {                    // t<16: batch0; 16..31: batch1
            const int bsel = t >> 4, o = t & 15;
            float s = 0.f;
#pragma unroll
            for (int w = 0; w < 16; ++w) s += red[bsel * 256 + w * 16 + o];
            s *= uni ? (1.0f / 1152.0f) : (bsel ? invd1 : invd0);
            float sq = s * s;
#pragma unroll
            for (int msk = 1; msk <= 8; msk <<= 1) sq += __shfl_xor(sq, msk, 64);
            float v = s * (sqrtf(sq) / (1.0f + sq));   // squash
            if (it == NITER - 1) out[((size_t)(b0 + bsel) * NC + c) * OC + o] = v;
            else vout[t] = v;
        }
        __syncthreads();

        if (it < NITER - 1) {
            // logit[r] += sum_o pri[r][o]*v[o]
            float4 v0 = ((const float4*)vout)[og];
            float4 v1 = ((const float4*)(vout + OC))[og];
#pragma unroll
            for (int p = 0; p < 4; ++p) {
                const int r = rr + (p << 8);
                float d0 = pri0[p].x * v0.x + pri0[p].y * v0.y +
                           pri0[p].z * v0.z + pri0[p].w * v0.w;
                float d1 = pri1[p].x * v1.x + pri1[p].y * v1.y +
                           pri1[p].z * v1.z + pri1[p].w * v1.w;
                d0 += __shfl_xor(d0, 1, 64); d1 += __shfl_xor(d1, 1, 64);
                d0 += __shfl_xor(d0, 2, 64); d1 += __shfl_xor(d1, 2, 64);
                if (og == 0) {
                    if (it == 0) { logit0[r] = d0; logit1[r] = d1; }
                    else         { logit0[r] += d0; logit1[r] += d1; }
                }
            }
            if (has4) {
                const int r = 1024 + rr;
                float d0 = pri0[4].x * v0.x + pri0[4].y * v0.y +
                           pri0[4].z * v0.z + pri0[4].w * v0.w;
                float d1 = pri1[4].x * v1.x + pri1[4].y * v1.y +
                           pri1[4].z * v1.z + pri1[4].w * v1.w;
                d0 += __shfl_xor(d0, 1, 64); d1 += __shfl_xor(d1, 1, 64);
                d0 += __shfl_xor(d0, 2, 64); d1 += __shfl_xor(d1, 2, 64);
                if (og == 0) {
                    if (it == 0) { logit0[r] = d0; logit1[r] = d1; }
                    else         { logit0[r] += d0; logit1[r] += d1; }
                }
            }
            __syncthreads();
        }
    }
}

extern "C" void kernel_launch(void* const* d_in, const int* in_sizes, int n_in,
                              void* d_out, int out_size, void* d_ws, size_t ws_size,
                              hipStream_t stream) {
    const float* x = (const float*)d_in[0];
    const float* W = (const float*)d_in[1];
    float* out = (float*)d_out;
    caps_route<<<dim3(NC * (256 / MB)), dim3(T), 0, stream>>>(x, W, out);
}